// Round 1
// baseline (323.978 us; speedup 1.0000x reference)
//
#include <hip/hip_runtime.h>
#include <hip/hip_bf16.h>

// Q8_0 fused dequant GEMV:
//   out[o] = sum_k scales[o,k] * (sum_{i<32} x[k*32+i] * q[o,k*32+i]) + bias[o]
// Shapes: x[1,4096] f32, q[14336,4096] int32 (values in [-127,127]),
//         scales[14336,128] f32, bias[14336] f32, out[1,14336] f32.
// Memory-bound: q traffic = 235 MB int32 -> HBM roofline ~38 us @ 6.3 TB/s.

constexpr int IN  = 4096;
constexpr int OUT = 14336;
constexpr int NB  = IN / 32;           // 128 scale blocks per row
constexpr int WAVES_PER_BLOCK = 4;     // 256 threads
constexpr int ITERS = IN / (64 * 4);   // 16 int4 loads per lane per row

__global__ __launch_bounds__(256) void gemv_q8(
    const float* __restrict__ x,
    const int*   __restrict__ q,
    const float* __restrict__ scales,
    const float* __restrict__ bias,
    float*       __restrict__ out)
{
    __shared__ float xs[IN];           // 16 KB: whole activation vector

    // cooperative stage of x into LDS (vectorized)
    const float4* x4 = reinterpret_cast<const float4*>(x);
    float4* xs4 = reinterpret_cast<float4*>(xs);
    for (int i = threadIdx.x; i < IN / 4; i += blockDim.x) {
        xs4[i] = x4[i];
    }
    __syncthreads();

    const int wave = threadIdx.x >> 6;
    const int lane = threadIdx.x & 63;
    const int row  = blockIdx.x * WAVES_PER_BLOCK + wave;   // grid sized exactly

    const int4*  qrow = reinterpret_cast<const int4*>(q + (size_t)row * IN);
    const float* srow = scales + (size_t)row * NB;

    float acc = 0.0f;
#pragma unroll
    for (int it = 0; it < ITERS; ++it) {
        const int idx = it * 64 + lane;      // int4 index within the row
        const int4  qq = qrow[idx];          // 16B coalesced load (dwordx4)
        const int   e  = idx * 4;            // element index; e/32 = scale block
        const float s  = srow[e >> 5];       // all 4 elems share one block
        const float4 xv = xs4[idx];          // ds_read_b128
        const float dot = xv.x * (float)qq.x + xv.y * (float)qq.y
                        + xv.z * (float)qq.z + xv.w * (float)qq.w;
        acc = fmaf(s, dot, acc);
    }

    // wave-64 butterfly reduction
#pragma unroll
    for (int off = 32; off > 0; off >>= 1)
        acc += __shfl_down(acc, off, 64);

    if (lane == 0)
        out[row] = acc + bias[row];
}

extern "C" void kernel_launch(void* const* d_in, const int* in_sizes, int n_in,
                              void* d_out, int out_size, void* d_ws, size_t ws_size,
                              hipStream_t stream) {
    const float* x      = (const float*)d_in[0];
    const int*   q      = (const int*)  d_in[1];
    const float* scales = (const float*)d_in[2];
    const float* bias   = (const float*)d_in[3];
    float*       out    = (float*)d_out;

    const int grid = OUT / WAVES_PER_BLOCK;   // 14336/4 = 3584, exact
    gemv_q8<<<grid, 64 * WAVES_PER_BLOCK, 0, stream>>>(x, q, scales, bias, out);
}

// Round 2
// 303.601 us; speedup vs baseline: 1.0671x; 1.0671x over previous
//
#include <hip/hip_runtime.h>
#include <hip/hip_bf16.h>

// Q8_0 fused dequant GEMV:
//   out[o] = sum_k scales[o,k] * (sum_{i<32} x[k*32+i] * q[o,k*32+i]) + bias[o]
// x[1,4096] f32, q[14336,4096] int32 in [-127,127], scales[14336,128] f32,
// bias[14336] f32, out[1,14336] f32.
// Memory-bound: q = 235 MB/call -> HBM floor ~38.6 us @ 6.3 TB/s.
// R1 measured ~46 us kernel (dur 324 incl. ~278 us harness poison fills).
// R2: nontemporal loads on the single-use q/scales streams to avoid evicting
// the reused x (57 MB of block-level refetch served by L1/L2/L3).

typedef int   int4v   __attribute__((ext_vector_type(4)));
typedef float float4v __attribute__((ext_vector_type(4)));

constexpr int IN  = 4096;
constexpr int OUT = 14336;
constexpr int NB  = IN / 32;           // 128 scale blocks per row
constexpr int WAVES_PER_BLOCK = 4;     // 256 threads
constexpr int ITERS = IN / (64 * 4);   // 16 int4 loads per lane per row

__global__ __launch_bounds__(256) void gemv_q8(
    const float* __restrict__ x,
    const int*   __restrict__ q,
    const float* __restrict__ scales,
    const float* __restrict__ bias,
    float*       __restrict__ out)
{
    __shared__ float4v xs4[IN / 4];    // 16 KB: whole activation vector

    // cooperative stage of x into LDS (vectorized, cache-friendly: x is reused
    // by every block so it stays in L2/L3)
    const float4v* x4 = reinterpret_cast<const float4v*>(x);
    for (int i = threadIdx.x; i < IN / 4; i += 256) {
        xs4[i] = x4[i];
    }
    __syncthreads();

    const int wave = threadIdx.x >> 6;
    const int lane = threadIdx.x & 63;
    const int row  = blockIdx.x * WAVES_PER_BLOCK + wave;   // grid sized exactly

    const int4v* qrow = reinterpret_cast<const int4v*>(q + (size_t)row * IN);
    const float* srow = scales + (size_t)row * NB;

    float acc = 0.0f;
#pragma unroll
    for (int it = 0; it < ITERS; ++it) {
        const int idx = it * 64 + lane;                   // int4 index in row
        // q and scales are single-use streams: nontemporal keeps them from
        // evicting the shared x vector out of L1/L2.
        const int4v qq = __builtin_nontemporal_load(qrow + idx);
        const float s  = __builtin_nontemporal_load(srow + (idx >> 3));
        const float4v xv = xs4[idx];                      // ds_read_b128
        const float dot = xv.x * (float)qq.x + xv.y * (float)qq.y
                        + xv.z * (float)qq.z + xv.w * (float)qq.w;
        acc = fmaf(s, dot, acc);
    }

    // wave-64 butterfly reduction
#pragma unroll
    for (int off = 32; off > 0; off >>= 1)
        acc += __shfl_down(acc, off, 64);

    if (lane == 0)
        out[row] = acc + bias[row];
}

extern "C" void kernel_launch(void* const* d_in, const int* in_sizes, int n_in,
                              void* d_out, int out_size, void* d_ws, size_t ws_size,
                              hipStream_t stream) {
    const float* x      = (const float*)d_in[0];
    const int*   q      = (const int*)  d_in[1];
    const float* scales = (const float*)d_in[2];
    const float* bias   = (const float*)d_in[3];
    float*       out    = (float*)d_out;

    const int grid = OUT / WAVES_PER_BLOCK;   // 14336/4 = 3584, exact
    gemv_q8<<<grid, 64 * WAVES_PER_BLOCK, 0, stream>>>(x, q, scales, bias, out);
}